// Round 7
// baseline (373.018 us; speedup 1.0000x reference)
//
#include <hip/hip_runtime.h>

typedef __bf16 bf16_t;
typedef __bf16 bf16x8 __attribute__((ext_vector_type(8)));
typedef float f32x4 __attribute__((ext_vector_type(4)));

#define NL 3
#define HD 128
#define ROWS 64
#define STR 136          // 128 data cols + 8 padding cols that hold bf16(x) (D_IN==8!)
#define THREADS 512
#define BATCH 262144
#define NBLK (BATCH / ROWS)

// ws (d_ws) layout in bf16 elements: weights pre-swizzled into MFMA B-fragment order
#define SW_OFF 0                 // [ct=8][lane=64][j=8]                       = 4096
#define U_OFF  4096              // [l=3][g=4][ct=8][lane=64][j=8]             = 49152
#define W_OFF  53248             // [l=3][g=4][ct=8][kc=4][lane=64][j=8]       = 196608
#define WS_ELEMS 249856          // total bf16 elems (499712 bytes)

#define MFMA(a, b, c) __builtin_amdgcn_mfma_f32_16x16x32_bf16((a), (b), (c), 0, 0, 0)

// 3-4 VALU activations (saturating limits exact: exp2->inf->rcp->0)
#define LOG2E 1.4426950408889634f
__device__ __forceinline__ float sigm(float v) {
    return __builtin_amdgcn_rcpf(1.f + __builtin_amdgcn_exp2f(-LOG2E * v));
}
__device__ __forceinline__ float sigmn(float v) {  // = 1 - sigm(v) = sigm(-v)
    return __builtin_amdgcn_rcpf(1.f + __builtin_amdgcn_exp2f(LOG2E * v));
}
__device__ __forceinline__ float tanh_f(float v) {
    return 1.f - 2.f * __builtin_amdgcn_rcpf(__builtin_amdgcn_exp2f((2.f * LOG2E) * v) + 1.f);
}

// ---------------- prep: swizzle f32 weights into bf16 MFMA B-fragment order in ws ----------------
// B-frag layout for mfma_f32_16x16x32_bf16: lane holds B[k = (lane>>4)*8 + j][n = lane&15]
__global__ void dgm_prep(const float* __restrict__ SwW,
                         const float* __restrict__ Uz, const float* __restrict__ Wz,
                         const float* __restrict__ Ug, const float* __restrict__ Wg,
                         const float* __restrict__ Ur, const float* __restrict__ Wr,
                         const float* __restrict__ Uh, const float* __restrict__ Wh,
                         bf16_t* __restrict__ ws) {
    int idx = blockIdx.x * 256 + threadIdx.x;
    if (idx >= WS_ELEMS) return;
    const float* Us[4] = {Uz, Ug, Ur, Uh};
    const float* Wm[4] = {Wz, Wg, Wr, Wh};
    if (idx < U_OFF) {
        int ct = idx >> 9, rem = idx & 511, lane = rem >> 3, j = rem & 7;
        int q = lane >> 4, mm = lane & 15;
        int k = q * 8 + j, n = ct * 16 + mm;
        ws[idx] = (k < 8) ? (bf16_t)SwW[k * HD + n] : (bf16_t)0.f;
    } else if (idx < W_OFF) {
        int t = idx - U_OFF;
        int lg = t >> 12, r2 = t & 4095;
        int l = lg >> 2, g = lg & 3;
        int ct = r2 >> 9, rem = r2 & 511, lane = rem >> 3, j = rem & 7;
        int q = lane >> 4, mm = lane & 15;
        int k = q * 8 + j, n = ct * 16 + mm;
        ws[idx] = (k < 8) ? (bf16_t)Us[g][(l * 8 + k) * HD + n] : (bf16_t)0.f;
    } else {
        int t = idx - W_OFF;
        int lg = t >> 14, r2 = t & 16383;
        int l = lg >> 2, g = lg & 3;
        int ct = r2 >> 11, kc = (r2 >> 9) & 3, rem = r2 & 511, lane = rem >> 3, j = rem & 7;
        int q = lane >> 4, mm = lane & 15;
        int k = kc * 32 + q * 8 + j, n = ct * 16 + mm;
        ws[idx] = (bf16_t)Wm[g][(l * HD + k) * HD + n];
    }
}

// ---------------- main fused kernel: x lives in the STR padding; no xf/sv registers ----------------
// x K-chunk A-frag is read at row*STR+128 for ALL quads (max offset 135 < STR): no overrun,
// q>=1 lanes read x (finite) times zero U-rows = 0. (Round-6 bug: +q*8 overran row 63 into
// the f32 red[] buffer whose bit patterns can alias bf16 NaN; NaN*0=NaN in MFMA.)
__global__ __launch_bounds__(THREADS, 4) void dgm_main(
    const float* __restrict__ x,
    const float* __restrict__ Swb,
    const float* __restrict__ Bz, const float* __restrict__ Bg,
    const float* __restrict__ Br, const float* __restrict__ Bh,
    const float* __restrict__ WfW, const float* __restrict__ WfB,
    const bf16_t* __restrict__ ws,
    float* __restrict__ out) {
    __shared__ __align__(16) bf16_t s_sig[2][ROWS * STR];  // sigma(S) ping-pong; cols 128..135 = bf16(x)
    __shared__ __align__(16) bf16_t s_r[ROWS * STR];       // sigma(S)*R;        cols 128..135 = bf16(x)
    __shared__ float red[ROWS];                            // final-dot reduction

    const int tid = threadIdx.x;
    const int lane = tid & 63;
    const int ct = tid >> 6;           // wave owns column tile ct (cols ct*16..ct*16+15), all 64 rows
    const int m = lane & 15, q = lane >> 4;
    const int rb = blockIdx.x * ROWS;
    const int c = ct * 16 + m;         // this thread's fixed output column
    const int fragoff = (ct * 64 + lane) * 8;

    if (tid < ROWS) red[tid] = 0.f;

    // stage bf16(x) into the padding columns of all three tiles (one element per thread)
    {
        int r = tid >> 3, j = tid & 7;
        bf16_t xv = (bf16_t)x[(size_t)(rb + r) * 8 + j];
        s_sig[0][r * STR + 128 + j] = xv;
        s_sig[1][r * STR + 128 + j] = xv;
        s_r[r * STR + 128 + j] = xv;
    }
    __syncthreads();

    // ---- init: S0 = x@Sw + b (x read from padding as A-frag); store sigma(S0)
    {
        const float swb = Swb[c];
        bf16x8 fSw = *(const bf16x8*)(ws + SW_OFF + fragoff);
#pragma unroll
        for (int rt = 0; rt < 4; rt++) {
            bf16x8 a = *(const bf16x8*)(&s_sig[0][(rt * 16 + m) * STR + 128]);
            f32x4 acc = {0.f, 0.f, 0.f, 0.f};
            acc = MFMA(a, fSw, acc);
#pragma unroll
            for (int i = 0; i < 4; i++)
                s_sig[0][(rt * 16 + q * 4 + i) * STR + c] = (bf16_t)sigm(acc[i] + swb);
        }
    }
    __syncthreads();

#pragma unroll 1
    for (int l = 0; l < NL; l++) {
        const int cur = l & 1, nxt = cur ^ 1;
        const bf16_t* wb = ws + W_OFF + (size_t)l * 4 * 16384;
        const bf16_t* ub = ws + U_OFF + (size_t)l * 4 * 4096;

        // ---- P_A: R only (5 weight frags live)
        {
            bf16x8 fUr = *(const bf16x8*)(ub + 2 * 4096 + fragoff);
            bf16x8 fWr[4];
#pragma unroll
            for (int kc = 0; kc < 4; kc++)
                fWr[kc] = *(const bf16x8*)(wb + 2 * 16384 + (ct * 4 + kc) * 512 + lane * 8);
            const float br = Br[l * HD + c];
#pragma unroll
            for (int rt = 0; rt < 4; rt++) {
                const bf16_t* sbase = &s_sig[cur][(rt * 16 + m) * STR];
                f32x4 aR = {0.f, 0.f, 0.f, 0.f};
#pragma unroll
                for (int kc = 0; kc < 4; kc++) {
                    bf16x8 a = *(const bf16x8*)(sbase + kc * 32 + q * 8);
                    aR = MFMA(a, fWr[kc], aR);
                }
                {
                    bf16x8 a = *(const bf16x8*)(sbase + 128);  // x chunk (no q*8: in-row, finite)
                    aR = MFMA(a, fUr, aR);
                }
#pragma unroll
                for (int i = 0; i < 4; i++) {
                    int r = rt * 16 + q * 4 + i;
                    float sb = (float)s_sig[cur][r * STR + c];
                    float rv = sigm(aR[i] + br);
                    s_r[r * STR + c] = (bf16_t)(rv * sb);
                }
            }
        }
        __syncthreads();

        // ---- P_B: Z, G, H together (15 weight frags live)
        {
            bf16x8 fUz = *(const bf16x8*)(ub + 0 * 4096 + fragoff);
            bf16x8 fUg = *(const bf16x8*)(ub + 1 * 4096 + fragoff);
            bf16x8 fUh = *(const bf16x8*)(ub + 3 * 4096 + fragoff);
            bf16x8 fWz[4], fWg[4], fWh[4];
#pragma unroll
            for (int kc = 0; kc < 4; kc++) {
                fWz[kc] = *(const bf16x8*)(wb + 0 * 16384 + (ct * 4 + kc) * 512 + lane * 8);
                fWg[kc] = *(const bf16x8*)(wb + 1 * 16384 + (ct * 4 + kc) * 512 + lane * 8);
                fWh[kc] = *(const bf16x8*)(wb + 3 * 16384 + (ct * 4 + kc) * 512 + lane * 8);
            }
            const float bz = Bz[l * HD + c], bg = Bg[l * HD + c], bh = Bh[l * HD + c];
            const bool last = (l == NL - 1);
            const float wfc = WfW[c];
#pragma unroll
            for (int rt = 0; rt < 4; rt++) {
                const bf16_t* sbase = &s_sig[cur][(rt * 16 + m) * STR];
                const bf16_t* rbase = &s_r[(rt * 16 + m) * STR];
                f32x4 aZ = {0.f, 0.f, 0.f, 0.f}, aG = {0.f, 0.f, 0.f, 0.f}, aH = {0.f, 0.f, 0.f, 0.f};
#pragma unroll
                for (int kc = 0; kc < 4; kc++) {
                    bf16x8 as = *(const bf16x8*)(sbase + kc * 32 + q * 8);
                    bf16x8 ar = *(const bf16x8*)(rbase + kc * 32 + q * 8);
                    aZ = MFMA(as, fWz[kc], aZ);
                    aG = MFMA(as, fWg[kc], aG);
                    aH = MFMA(ar, fWh[kc], aH);
                }
                {
                    bf16x8 as = *(const bf16x8*)(sbase + 128);  // x chunk (no q*8: in-row, finite)
                    bf16x8 ar = *(const bf16x8*)(rbase + 128);
                    aZ = MFMA(as, fUz, aZ);
                    aG = MFMA(as, fUg, aG);
                    aH = MFMA(ar, fUh, aH);
                }
#pragma unroll
                for (int i = 0; i < 4; i++) {
                    int r = rt * 16 + q * 4 + i;
                    float sb = (float)s_sig[cur][r * STR + c];
                    float z = sigm(aZ[i] + bz);
                    float og = sigmn(aG[i] + bg);      // 1 - G
                    float hh = tanh_f(aH[i] + bh);
                    float sn = og * hh + z * sb;
                    if (last) {
                        float p = sn * wfc;            // S3 stays f32: fold S3@Wf into epilogue
                        p += __shfl_xor(p, 1);
                        p += __shfl_xor(p, 2);
                        p += __shfl_xor(p, 4);
                        p += __shfl_xor(p, 8);
                        if (m == 0) atomicAdd(&red[r], p);
                    } else {
                        s_sig[nxt][r * STR + c] = (bf16_t)sigm(sn);
                    }
                }
            }
        }
        __syncthreads();
    }

    if (tid < ROWS) out[rb + tid] = red[tid] + WfB[0];
}

extern "C" void kernel_launch(void* const* d_in, const int* in_sizes, int n_in,
                              void* d_out, int out_size, void* d_ws, size_t ws_size,
                              hipStream_t stream) {
    const float* x   = (const float*)d_in[0];
    const float* SwW = (const float*)d_in[1];
    const float* Swb = (const float*)d_in[2];
    const float* Uz  = (const float*)d_in[3];
    const float* Wz  = (const float*)d_in[4];
    const float* Bz  = (const float*)d_in[5];
    const float* Ug  = (const float*)d_in[6];
    const float* Wg  = (const float*)d_in[7];
    const float* Bg  = (const float*)d_in[8];
    const float* Ur  = (const float*)d_in[9];
    const float* Wr  = (const float*)d_in[10];
    const float* Br  = (const float*)d_in[11];
    const float* Uh  = (const float*)d_in[12];
    const float* Wh  = (const float*)d_in[13];
    const float* Bh  = (const float*)d_in[14];
    const float* WfW = (const float*)d_in[15];
    const float* WfB = (const float*)d_in[16];
    bf16_t* ws = (bf16_t*)d_ws;
    float* out = (float*)d_out;

    if (ws_size < (size_t)WS_ELEMS * sizeof(bf16_t)) return;  // need ~500 KB scratch

    dgm_prep<<<(WS_ELEMS + 255) / 256, 256, 0, stream>>>(SwW, Uz, Wz, Ug, Wg, Ur, Wr, Uh, Wh, ws);
    dgm_main<<<NBLK, THREADS, 0, stream>>>(x, Swb, Bz, Bg, Br, Bh, WfW, WfB, ws, out);
}

// Round 8
// 311.825 us; speedup vs baseline: 1.1962x; 1.1962x over previous
//
#include <hip/hip_runtime.h>

typedef __bf16 bf16_t;
typedef __bf16 bf16x2 __attribute__((ext_vector_type(2)));
typedef __bf16 bf16x8 __attribute__((ext_vector_type(8)));
typedef float f32x4 __attribute__((ext_vector_type(4)));

#define NL 3
#define HD 128
#define ROWS 64
#define STR 136          // 128 data cols + 8 padding cols that hold bf16(x) (D_IN==8!)
#define THREADS 512
#define BATCH 262144
#define NBLK (BATCH / ROWS)

// ws (d_ws) layout in bf16 elements: weights pre-swizzled into MFMA B-fragment order
#define SW_OFF 0                 // [ct=8][lane=64][j=8]                       = 4096
#define U_OFF  4096              // [l=3][g=4][ct=8][lane=64][j=8]             = 49152
#define W_OFF  53248             // [l=3][g=4][ct=8][kc=4][lane=64][j=8]       = 196608
#define WS_ELEMS 249856          // total bf16 elems (499712 bytes)

#define MFMA(a, b, c) __builtin_amdgcn_mfma_f32_16x16x32_bf16((a), (b), (c), 0, 0, 0)

// 3-4 VALU activations (saturating limits exact: exp2->inf->rcp->0)
#define LOG2E 1.4426950408889634f
__device__ __forceinline__ float sigm(float v) {
    return __builtin_amdgcn_rcpf(1.f + __builtin_amdgcn_exp2f(-LOG2E * v));
}
__device__ __forceinline__ float sigmn(float v) {  // = 1 - sigm(v) = sigm(-v)
    return __builtin_amdgcn_rcpf(1.f + __builtin_amdgcn_exp2f(LOG2E * v));
}
__device__ __forceinline__ float tanh_f(float v) {
    return 1.f - 2.f * __builtin_amdgcn_rcpf(__builtin_amdgcn_exp2f((2.f * LOG2E) * v) + 1.f);
}

// ---------------- prep: swizzle f32 weights into bf16 MFMA B-fragment order in ws ----------------
// B-frag layout for mfma_f32_16x16x32_bf16: lane holds B[k = (lane>>4)*8 + j][n = lane&15]
__global__ void dgm_prep(const float* __restrict__ SwW,
                         const float* __restrict__ Uz, const float* __restrict__ Wz,
                         const float* __restrict__ Ug, const float* __restrict__ Wg,
                         const float* __restrict__ Ur, const float* __restrict__ Wr,
                         const float* __restrict__ Uh, const float* __restrict__ Wh,
                         bf16_t* __restrict__ ws) {
    int idx = blockIdx.x * 256 + threadIdx.x;
    if (idx >= WS_ELEMS) return;
    const float* Us[4] = {Uz, Ug, Ur, Uh};
    const float* Wm[4] = {Wz, Wg, Wr, Wh};
    if (idx < U_OFF) {
        int ct = idx >> 9, rem = idx & 511, lane = rem >> 3, j = rem & 7;
        int q = lane >> 4, mm = lane & 15;
        int k = q * 8 + j, n = ct * 16 + mm;
        ws[idx] = (k < 8) ? (bf16_t)SwW[k * HD + n] : (bf16_t)0.f;
    } else if (idx < W_OFF) {
        int t = idx - U_OFF;
        int lg = t >> 12, r2 = t & 4095;
        int l = lg >> 2, g = lg & 3;
        int ct = r2 >> 9, rem = r2 & 511, lane = rem >> 3, j = rem & 7;
        int q = lane >> 4, mm = lane & 15;
        int k = q * 8 + j, n = ct * 16 + mm;
        ws[idx] = (k < 8) ? (bf16_t)Us[g][(l * 8 + k) * HD + n] : (bf16_t)0.f;
    } else {
        int t = idx - W_OFF;
        int lg = t >> 14, r2 = t & 16383;
        int l = lg >> 2, g = lg & 3;
        int ct = r2 >> 11, kc = (r2 >> 9) & 3, rem = r2 & 511, lane = rem >> 3, j = rem & 7;
        int q = lane >> 4, mm = lane & 15;
        int k = kc * 32 + q * 8 + j, n = ct * 16 + mm;
        ws[idx] = (bf16_t)Wm[g][(l * HD + k) * HD + n];
    }
}

// one gate's matmul for one row-tile: 4 K-chunks from `abase` + x-chunk (abase+128) vs fU
__device__ __forceinline__ f32x4 gate_mm(const bf16_t* abase, const bf16x8* fW, bf16x8 fU) {
    f32x4 acc = {0.f, 0.f, 0.f, 0.f};
#pragma unroll
    for (int kc = 0; kc < 4; kc++) {
        bf16x8 a = *(const bf16x8*)(abase + kc * 32);
        acc = MFMA(a, fW[kc], acc);
    }
    bf16x8 ax = *(const bf16x8*)(abase - ((reinterpret_cast<uintptr_t>(abase) / 2) % STR) + 0);  // unused; see caller
    return acc;
}

// ---------------- main fused kernel ----------------
// Phase plan per layer (2 barriers): P_A(R)->bar ; P_Z ; P_G ; P_H+update ->bar.
// P_Z/P_G/P_H need no barriers between them: they read only s_sig[cur]/s_r (stable since
// P_A's barrier) and write only own registers / own-column LDS elements. Each phase holds
// exactly 5 weight frags (20 VGPRs) so the 64-arch-VGPR budget of (512,4) never spills.
__global__ __launch_bounds__(THREADS, 4) void dgm_main(
    const float* __restrict__ x,
    const float* __restrict__ Swb,
    const float* __restrict__ Bz, const float* __restrict__ Bg,
    const float* __restrict__ Br, const float* __restrict__ Bh,
    const float* __restrict__ WfW, const float* __restrict__ WfB,
    const bf16_t* __restrict__ ws,
    float* __restrict__ out) {
    __shared__ __align__(16) bf16_t s_sig[2][ROWS * STR];  // sigma(S) ping-pong; cols 128..135 = bf16(x)
    __shared__ __align__(16) bf16_t s_r[ROWS * STR];       // sigma(S)*R;        cols 128..135 = bf16(x)
    __shared__ float red[ROWS];                            // final-dot reduction

    const int tid = threadIdx.x;
    const int lane = tid & 63;
    const int ct = tid >> 6;           // wave owns column tile ct (cols ct*16..ct*16+15), all 64 rows
    const int m = lane & 15, q = lane >> 4;
    const int rb = blockIdx.x * ROWS;
    const int c = ct * 16 + m;         // this thread's fixed output column
    const int fragoff = (ct * 64 + lane) * 8;

    if (tid < ROWS) red[tid] = 0.f;

    // stage bf16(x) into the padding columns (one element per thread)
    {
        int r = tid >> 3, j = tid & 7;
        bf16_t xv = (bf16_t)x[(size_t)(rb + r) * 8 + j];
        s_sig[0][r * STR + 128 + j] = xv;
        s_sig[1][r * STR + 128 + j] = xv;
        s_r[r * STR + 128 + j] = xv;
    }
    __syncthreads();

    // ---- init: S0 = x@Sw + b (x read from padding as A-frag, no q*8: in-row, finite)
    {
        const float swb = Swb[c];
        bf16x8 fSw = *(const bf16x8*)(ws + SW_OFF + fragoff);
#pragma unroll
        for (int rt = 0; rt < 4; rt++) {
            bf16x8 a = *(const bf16x8*)(&s_sig[0][(rt * 16 + m) * STR + 128]);
            f32x4 acc = {0.f, 0.f, 0.f, 0.f};
            acc = MFMA(a, fSw, acc);
#pragma unroll
            for (int i = 0; i < 4; i++)
                s_sig[0][(rt * 16 + q * 4 + i) * STR + c] = (bf16_t)sigm(acc[i] + swb);
        }
    }
    __syncthreads();

#pragma unroll 1
    for (int l = 0; l < NL; l++) {
        const int cur = l & 1, nxt = cur ^ 1;
        const bf16_t* wb = ws + W_OFF + (size_t)l * 4 * 16384;
        const bf16_t* ub = ws + U_OFF + (size_t)l * 4 * 4096;

        // ---- P_A: R -> s_r
        {
            bf16x8 fU = *(const bf16x8*)(ub + 2 * 4096 + fragoff);
            bf16x8 fW[4];
#pragma unroll
            for (int kc = 0; kc < 4; kc++)
                fW[kc] = *(const bf16x8*)(wb + 2 * 16384 + (ct * 4 + kc) * 512 + lane * 8);
            const float br = Br[l * HD + c];
#pragma unroll
            for (int rt = 0; rt < 4; rt++) {
                const bf16_t* abase = &s_sig[cur][(rt * 16 + m) * STR];
                f32x4 aR = {0.f, 0.f, 0.f, 0.f};
#pragma unroll
                for (int kc = 0; kc < 4; kc++) {
                    bf16x8 a = *(const bf16x8*)(abase + kc * 32 + q * 8);
                    aR = MFMA(a, fW[kc], aR);
                }
                {
                    bf16x8 a = *(const bf16x8*)(abase + 128);  // x chunk
                    aR = MFMA(a, fU, aR);
                }
#pragma unroll
                for (int i = 0; i < 4; i++) {
                    int r = rt * 16 + q * 4 + i;
                    float sb = (float)s_sig[cur][r * STR + c];
                    s_r[r * STR + c] = (bf16_t)(sigm(aR[i] + br) * sb);
                }
            }
        }
        __syncthreads();

        bf16x2 t1p[4][2];  // z*sigma(S), packed bf16 (carried across phases, 8 VGPRs)
        bf16x2 ogp[4][2];  // 1-G,        packed bf16 (8 VGPRs)

        // ---- P_Z: z*sb -> t1p
        {
            bf16x8 fU = *(const bf16x8*)(ub + 0 * 4096 + fragoff);
            bf16x8 fW[4];
#pragma unroll
            for (int kc = 0; kc < 4; kc++)
                fW[kc] = *(const bf16x8*)(wb + 0 * 16384 + (ct * 4 + kc) * 512 + lane * 8);
            const float bz = Bz[l * HD + c];
#pragma unroll
            for (int rt = 0; rt < 4; rt++) {
                const bf16_t* abase = &s_sig[cur][(rt * 16 + m) * STR];
                f32x4 aZ = {0.f, 0.f, 0.f, 0.f};
#pragma unroll
                for (int kc = 0; kc < 4; kc++) {
                    bf16x8 a = *(const bf16x8*)(abase + kc * 32 + q * 8);
                    aZ = MFMA(a, fW[kc], aZ);
                }
                {
                    bf16x8 a = *(const bf16x8*)(abase + 128);
                    aZ = MFMA(a, fU, aZ);
                }
#pragma unroll
                for (int i = 0; i < 4; i++) {
                    int r = rt * 16 + q * 4 + i;
                    float sb = (float)s_sig[cur][r * STR + c];
                    t1p[rt][i >> 1][i & 1] = (bf16_t)(sigm(aZ[i] + bz) * sb);
                }
            }
        }

        // ---- P_G: 1-G -> ogp (no barrier needed: reads stable LDS, writes regs only)
        {
            bf16x8 fU = *(const bf16x8*)(ub + 1 * 4096 + fragoff);
            bf16x8 fW[4];
#pragma unroll
            for (int kc = 0; kc < 4; kc++)
                fW[kc] = *(const bf16x8*)(wb + 1 * 16384 + (ct * 4 + kc) * 512 + lane * 8);
            const float bg = Bg[l * HD + c];
#pragma unroll
            for (int rt = 0; rt < 4; rt++) {
                const bf16_t* abase = &s_sig[cur][(rt * 16 + m) * STR];
                f32x4 aG = {0.f, 0.f, 0.f, 0.f};
#pragma unroll
                for (int kc = 0; kc < 4; kc++) {
                    bf16x8 a = *(const bf16x8*)(abase + kc * 32 + q * 8);
                    aG = MFMA(a, fW[kc], aG);
                }
                {
                    bf16x8 a = *(const bf16x8*)(abase + 128);
                    aG = MFMA(a, fU, aG);
                }
#pragma unroll
                for (int i = 0; i < 4; i++)
                    ogp[rt][i >> 1][i & 1] = (bf16_t)sigmn(aG[i] + bg);
            }
        }

        // ---- P_H + state update (reads s_r; writes s_sig[nxt] own elems / final dot)
        {
            bf16x8 fU = *(const bf16x8*)(ub + 3 * 4096 + fragoff);
            bf16x8 fW[4];
#pragma unroll
            for (int kc = 0; kc < 4; kc++)
                fW[kc] = *(const bf16x8*)(wb + 3 * 16384 + (ct * 4 + kc) * 512 + lane * 8);
            const float bh = Bh[l * HD + c];
            const bool last = (l == NL - 1);
            const float wfc = WfW[c];
#pragma unroll
            for (int rt = 0; rt < 4; rt++) {
                const bf16_t* abase = &s_r[(rt * 16 + m) * STR];
                f32x4 aH = {0.f, 0.f, 0.f, 0.f};
#pragma unroll
                for (int kc = 0; kc < 4; kc++) {
                    bf16x8 a = *(const bf16x8*)(abase + kc * 32 + q * 8);
                    aH = MFMA(a, fW[kc], aH);
                }
                {
                    bf16x8 a = *(const bf16x8*)(abase + 128);
                    aH = MFMA(a, fU, aH);
                }
#pragma unroll
                for (int i = 0; i < 4; i++) {
                    int r = rt * 16 + q * 4 + i;
                    float hh = tanh_f(aH[i] + bh);
                    float sn = (float)ogp[rt][i >> 1][i & 1] * hh + (float)t1p[rt][i >> 1][i & 1];
                    if (last) {
                        float p = sn * wfc;            // fold S3@Wf into epilogue, S3 stays f32
                        p += __shfl_xor(p, 1);
                        p += __shfl_xor(p, 2);
                        p += __shfl_xor(p, 4);
                        p += __shfl_xor(p, 8);
                        if (m == 0) atomicAdd(&red[r], p);
                    } else {
                        s_sig[nxt][r * STR + c] = (bf16_t)sigm(sn);
                    }
                }
            }
        }
        __syncthreads();
    }

    if (tid < ROWS) out[rb + tid] = red[tid] + WfB[0];
}

extern "C" void kernel_launch(void* const* d_in, const int* in_sizes, int n_in,
                              void* d_out, int out_size, void* d_ws, size_t ws_size,
                              hipStream_t stream) {
    const float* x   = (const float*)d_in[0];
    const float* SwW = (const float*)d_in[1];
    const float* Swb = (const float*)d_in[2];
    const float* Uz  = (const float*)d_in[3];
    const float* Wz  = (const float*)d_in[4];
    const float* Bz  = (const float*)d_in[5];
    const float* Ug  = (const float*)d_in[6];
    const float* Wg  = (const float*)d_in[7];
    const float* Bg  = (const float*)d_in[8];
    const float* Ur  = (const float*)d_in[9];
    const float* Wr  = (const float*)d_in[10];
    const float* Br  = (const float*)d_in[11];
    const float* Uh  = (const float*)d_in[12];
    const float* Wh  = (const float*)d_in[13];
    const float* Bh  = (const float*)d_in[14];
    const float* WfW = (const float*)d_in[15];
    const float* WfB = (const float*)d_in[16];
    bf16_t* ws = (bf16_t*)d_ws;
    float* out = (float*)d_out;

    if (ws_size < (size_t)WS_ELEMS * sizeof(bf16_t)) return;  // need ~500 KB scratch

    dgm_prep<<<(WS_ELEMS + 255) / 256, 256, 0, stream>>>(SwW, Uz, Wz, Ug, Wg, Ur, Wr, Uh, Wh, ws);
    dgm_main<<<NBLK, THREADS, 0, stream>>>(x, Swb, Bz, Bg, Br, Bh, WfW, WfB, ws, out);
}

// Round 9
// 298.337 us; speedup vs baseline: 1.2503x; 1.0452x over previous
//
#include <hip/hip_runtime.h>

typedef __bf16 bf16_t;
typedef __bf16 bf16x2 __attribute__((ext_vector_type(2)));
typedef __bf16 bf16x8 __attribute__((ext_vector_type(8)));
typedef float f32x4 __attribute__((ext_vector_type(4)));

#define NL 3
#define HD 128
#define ROWS 64
#define STR 136          // 128 data cols + 8 padding cols that hold bf16(x) (D_IN==8!)
#define THREADS 512
#define BATCH 262144
#define NBLK (BATCH / ROWS)

// ws (d_ws) layout in bf16 elements: weights pre-swizzled into MFMA B-fragment order
#define SW_OFF 0                 // [ct=8][lane=64][j=8]                       = 4096
#define U_OFF  4096              // [l=3][g=4][ct=8][lane=64][j=8]             = 49152
#define W_OFF  53248             // [l=3][g=4][ct=8][kc=4][lane=64][j=8]       = 196608
#define WS_ELEMS 249856          // total bf16 elems (499712 bytes)

#define MFMA(a, b, c) __builtin_amdgcn_mfma_f32_16x16x32_bf16((a), (b), (c), 0, 0, 0)

// 3-4 VALU activations (saturating limits exact: exp2->inf->rcp->0)
#define LOG2E 1.4426950408889634f
__device__ __forceinline__ float sigm(float v) {
    return __builtin_amdgcn_rcpf(1.f + __builtin_amdgcn_exp2f(-LOG2E * v));
}
__device__ __forceinline__ float sigmn(float v) {  // = 1 - sigm(v) = sigm(-v)
    return __builtin_amdgcn_rcpf(1.f + __builtin_amdgcn_exp2f(LOG2E * v));
}
__device__ __forceinline__ float tanh_f(float v) {
    return 1.f - 2.f * __builtin_amdgcn_rcpf(__builtin_amdgcn_exp2f((2.f * LOG2E) * v) + 1.f);
}

// ---------------- prep: swizzle f32 weights into bf16 MFMA B-fragment order in ws ----------------
// B-frag layout for mfma_f32_16x16x32_bf16: lane holds B[k = (lane>>4)*8 + j][n = lane&15]
__global__ void dgm_prep(const float* __restrict__ SwW,
                         const float* __restrict__ Uz, const float* __restrict__ Wz,
                         const float* __restrict__ Ug, const float* __restrict__ Wg,
                         const float* __restrict__ Ur, const float* __restrict__ Wr,
                         const float* __restrict__ Uh, const float* __restrict__ Wh,
                         bf16_t* __restrict__ ws) {
    int idx = blockIdx.x * 256 + threadIdx.x;
    if (idx >= WS_ELEMS) return;
    const float* Us[4] = {Uz, Ug, Ur, Uh};
    const float* Wm[4] = {Wz, Wg, Wr, Wh};
    if (idx < U_OFF) {
        int ct = idx >> 9, rem = idx & 511, lane = rem >> 3, j = rem & 7;
        int q = lane >> 4, mm = lane & 15;
        int k = q * 8 + j, n = ct * 16 + mm;
        ws[idx] = (k < 8) ? (bf16_t)SwW[k * HD + n] : (bf16_t)0.f;
    } else if (idx < W_OFF) {
        int t = idx - U_OFF;
        int lg = t >> 12, r2 = t & 4095;
        int l = lg >> 2, g = lg & 3;
        int ct = r2 >> 9, rem = r2 & 511, lane = rem >> 3, j = rem & 7;
        int q = lane >> 4, mm = lane & 15;
        int k = q * 8 + j, n = ct * 16 + mm;
        ws[idx] = (k < 8) ? (bf16_t)Us[g][(l * 8 + k) * HD + n] : (bf16_t)0.f;
    } else {
        int t = idx - W_OFF;
        int lg = t >> 14, r2 = t & 16383;
        int l = lg >> 2, g = lg & 3;
        int ct = r2 >> 11, kc = (r2 >> 9) & 3, rem = r2 & 511, lane = rem >> 3, j = rem & 7;
        int q = lane >> 4, mm = lane & 15;
        int k = kc * 32 + q * 8 + j, n = ct * 16 + mm;
        ws[idx] = (bf16_t)Wm[g][(l * HD + k) * HD + n];
    }
}

// ---------------- main fused kernel ----------------
// Phase plan per layer (2 barriers): P_A(R)->bar ; P_ZG (Z+G share A-frags) ; P_H+update ->bar.
// P_ZG/P_H need no barrier between them: they read only s_sig[cur]/s_r (stable since P_A's
// barrier) and write only own registers / own-column LDS elements. sigma(S) at this thread's
// 16 epilogue elements is carried in packed bf16 regs (svp) -> zero scalar LDS re-reads.
__global__ __launch_bounds__(THREADS, 4) void dgm_main(
    const float* __restrict__ x,
    const float* __restrict__ Swb,
    const float* __restrict__ Bz, const float* __restrict__ Bg,
    const float* __restrict__ Br, const float* __restrict__ Bh,
    const float* __restrict__ WfW, const float* __restrict__ WfB,
    const bf16_t* __restrict__ ws,
    float* __restrict__ out) {
    __shared__ __align__(16) bf16_t s_sig[2][ROWS * STR];  // sigma(S) ping-pong; cols 128..135 = bf16(x)
    __shared__ __align__(16) bf16_t s_r[ROWS * STR];       // sigma(S)*R;        cols 128..135 = bf16(x)
    __shared__ float red[ROWS];                            // final-dot reduction

    const int tid = threadIdx.x;
    const int lane = tid & 63;
    const int ct = tid >> 6;           // wave owns column tile ct (cols ct*16..ct*16+15), all 64 rows
    const int m = lane & 15, q = lane >> 4;
    const int rb = blockIdx.x * ROWS;
    const int c = ct * 16 + m;         // this thread's fixed output column
    const int fragoff = (ct * 64 + lane) * 8;

    if (tid < ROWS) red[tid] = 0.f;

    // stage bf16(x) into the padding columns (one element per thread)
    {
        int r = tid >> 3, j = tid & 7;
        bf16_t xv = (bf16_t)x[(size_t)(rb + r) * 8 + j];
        s_sig[0][r * STR + 128 + j] = xv;
        s_sig[1][r * STR + 128 + j] = xv;
        s_r[r * STR + 128 + j] = xv;
    }
    __syncthreads();

    bf16x2 svp[4][2];  // sigma(S) at this thread's 16 elements, packed (8 VGPRs)

    // ---- init: S0 = x@Sw + b (x read from padding as A-frag, no q*8: in-row, finite)
    {
        const float swb = Swb[c];
        bf16x8 fSw = *(const bf16x8*)(ws + SW_OFF + fragoff);
#pragma unroll
        for (int rt = 0; rt < 4; rt++) {
            bf16x8 a = *(const bf16x8*)(&s_sig[0][(rt * 16 + m) * STR + 128]);
            f32x4 acc = {0.f, 0.f, 0.f, 0.f};
            acc = MFMA(a, fSw, acc);
#pragma unroll
            for (int i = 0; i < 4; i++) {
                bf16_t s0 = (bf16_t)sigm(acc[i] + swb);
                svp[rt][i >> 1][i & 1] = s0;
                s_sig[0][(rt * 16 + q * 4 + i) * STR + c] = s0;
            }
        }
    }
    __syncthreads();

#pragma unroll 1
    for (int l = 0; l < NL; l++) {
        const int cur = l & 1, nxt = cur ^ 1;
        const bf16_t* wb = ws + W_OFF + (size_t)l * 4 * 16384;
        const bf16_t* ub = ws + U_OFF + (size_t)l * 4 * 4096;

        // ---- P_A: R -> s_r  (5 weight frags live)
        {
            bf16x8 fU = *(const bf16x8*)(ub + 2 * 4096 + fragoff);
            bf16x8 fW[4];
#pragma unroll
            for (int kc = 0; kc < 4; kc++)
                fW[kc] = *(const bf16x8*)(wb + 2 * 16384 + (ct * 4 + kc) * 512 + lane * 8);
            const float br = Br[l * HD + c];
#pragma unroll
            for (int rt = 0; rt < 4; rt++) {
                const bf16_t* abase = &s_sig[cur][(rt * 16 + m) * STR];
                f32x4 aR = {0.f, 0.f, 0.f, 0.f};
#pragma unroll
                for (int kc = 0; kc < 4; kc++) {
                    bf16x8 a = *(const bf16x8*)(abase + kc * 32 + q * 8);
                    aR = MFMA(a, fW[kc], aR);
                }
                {
                    bf16x8 a = *(const bf16x8*)(abase + 128);  // x chunk
                    aR = MFMA(a, fU, aR);
                }
#pragma unroll
                for (int i = 0; i < 4; i++) {
                    int r = rt * 16 + q * 4 + i;
                    float sb = (float)svp[rt][i >> 1][i & 1];
                    s_r[r * STR + c] = (bf16_t)(sigm(aR[i] + br) * sb);
                }
            }
        }
        __syncthreads();

        bf16x2 t1p[4][2];  // z*sigma(S), packed bf16 (8 VGPRs, carried to P_H)
        bf16x2 ogp[4][2];  // 1-G,        packed bf16 (8 VGPRs)

        // ---- P_ZG: Z and G share each A-fragment read (10 weight frags live)
        {
            bf16x8 fUz = *(const bf16x8*)(ub + 0 * 4096 + fragoff);
            bf16x8 fUg = *(const bf16x8*)(ub + 1 * 4096 + fragoff);
            bf16x8 fWz[4], fWg[4];
#pragma unroll
            for (int kc = 0; kc < 4; kc++) {
                fWz[kc] = *(const bf16x8*)(wb + 0 * 16384 + (ct * 4 + kc) * 512 + lane * 8);
                fWg[kc] = *(const bf16x8*)(wb + 1 * 16384 + (ct * 4 + kc) * 512 + lane * 8);
            }
            const float bz = Bz[l * HD + c], bg = Bg[l * HD + c];
#pragma unroll
            for (int rt = 0; rt < 4; rt++) {
                const bf16_t* abase = &s_sig[cur][(rt * 16 + m) * STR];
                f32x4 aZ = {0.f, 0.f, 0.f, 0.f}, aG = {0.f, 0.f, 0.f, 0.f};
#pragma unroll
                for (int kc = 0; kc < 4; kc++) {
                    bf16x8 a = *(const bf16x8*)(abase + kc * 32 + q * 8);
                    aZ = MFMA(a, fWz[kc], aZ);
                    aG = MFMA(a, fWg[kc], aG);
                }
                {
                    bf16x8 a = *(const bf16x8*)(abase + 128);  // x chunk
                    aZ = MFMA(a, fUz, aZ);
                    aG = MFMA(a, fUg, aG);
                }
#pragma unroll
                for (int i = 0; i < 4; i++) {
                    float sb = (float)svp[rt][i >> 1][i & 1];
                    t1p[rt][i >> 1][i & 1] = (bf16_t)(sigm(aZ[i] + bz) * sb);
                    ogp[rt][i >> 1][i & 1] = (bf16_t)sigmn(aG[i] + bg);
                }
            }
        }

        // ---- P_H + state update (reads s_r; writes s_sig[nxt] own elems / final dot)
        {
            bf16x8 fU = *(const bf16x8*)(ub + 3 * 4096 + fragoff);
            bf16x8 fW[4];
#pragma unroll
            for (int kc = 0; kc < 4; kc++)
                fW[kc] = *(const bf16x8*)(wb + 3 * 16384 + (ct * 4 + kc) * 512 + lane * 8);
            const float bh = Bh[l * HD + c];
            const bool last = (l == NL - 1);
            const float wfc = WfW[c];
#pragma unroll
            for (int rt = 0; rt < 4; rt++) {
                const bf16_t* abase = &s_r[(rt * 16 + m) * STR];
                f32x4 aH = {0.f, 0.f, 0.f, 0.f};
#pragma unroll
                for (int kc = 0; kc < 4; kc++) {
                    bf16x8 a = *(const bf16x8*)(abase + kc * 32 + q * 8);
                    aH = MFMA(a, fW[kc], aH);
                }
                {
                    bf16x8 a = *(const bf16x8*)(abase + 128);  // x chunk
                    aH = MFMA(a, fU, aH);
                }
#pragma unroll
                for (int i = 0; i < 4; i++) {
                    int r = rt * 16 + q * 4 + i;
                    float hh = tanh_f(aH[i] + bh);
                    float sn = (float)ogp[rt][i >> 1][i & 1] * hh + (float)t1p[rt][i >> 1][i & 1];
                    if (last) {
                        float p = sn * wfc;            // fold S3@Wf into epilogue, S3 stays f32
                        p += __shfl_xor(p, 1);
                        p += __shfl_xor(p, 2);
                        p += __shfl_xor(p, 4);
                        p += __shfl_xor(p, 8);
                        if (m == 0) atomicAdd(&red[r], p);
                    } else {
                        bf16_t s2 = (bf16_t)sigm(sn);
                        svp[rt][i >> 1][i & 1] = s2;
                        s_sig[nxt][r * STR + c] = s2;
                    }
                }
            }
        }
        __syncthreads();
    }

    if (tid < ROWS) out[rb + tid] = red[tid] + WfB[0];
}

extern "C" void kernel_launch(void* const* d_in, const int* in_sizes, int n_in,
                              void* d_out, int out_size, void* d_ws, size_t ws_size,
                              hipStream_t stream) {
    const float* x   = (const float*)d_in[0];
    const float* SwW = (const float*)d_in[1];
    const float* Swb = (const float*)d_in[2];
    const float* Uz  = (const float*)d_in[3];
    const float* Wz  = (const float*)d_in[4];
    const float* Bz  = (const float*)d_in[5];
    const float* Ug  = (const float*)d_in[6];
    const float* Wg  = (const float*)d_in[7];
    const float* Bg  = (const float*)d_in[8];
    const float* Ur  = (const float*)d_in[9];
    const float* Wr  = (const float*)d_in[10];
    const float* Br  = (const float*)d_in[11];
    const float* Uh  = (const float*)d_in[12];
    const float* Wh  = (const float*)d_in[13];
    const float* Bh  = (const float*)d_in[14];
    const float* WfW = (const float*)d_in[15];
    const float* WfB = (const float*)d_in[16];
    bf16_t* ws = (bf16_t*)d_ws;
    float* out = (float*)d_out;

    if (ws_size < (size_t)WS_ELEMS * sizeof(bf16_t)) return;  // need ~500 KB scratch

    dgm_prep<<<(WS_ELEMS + 255) / 256, 256, 0, stream>>>(SwW, Uz, Wz, Ug, Wg, Ur, Wr, Uh, Wh, ws);
    dgm_main<<<NBLK, THREADS, 0, stream>>>(x, Swb, Bz, Bg, Br, Bh, WfW, WfB, ws, out);
}